// Round 1
// baseline (51.897 us; speedup 1.0000x reference)
//
#include <hip/hip_runtime.h>
#include <math.h>

// CropPoolLayer: TF crop_and_resize (bilinear, extrapolation=0) to 14x14
// fused with 2x2 max pool -> [N,7,7,C], NHWC fp32.
//
// Shapes (from reference setup): bottom [B=2,H=64,W=64,C=512] fp32,
// rois [N=512,5] (batch_id,x1,y1,x2,y2), im_info [2] (h,w). Out [N,7,7,512].

constexpr int POOLSZ = 7;
constexpr int CROPSZ = 14;

__device__ __forceinline__ float4 f4max(float4 a, float4 b) {
    return make_float4(fmaxf(a.x, b.x), fmaxf(a.y, b.y),
                       fmaxf(a.z, b.z), fmaxf(a.w, b.w));
}

// a + (b-a)*t  — matches reference lerp ordering
__device__ __forceinline__ float4 lerp4(float4 a, float4 b, float t) {
    return make_float4(fmaf(b.x - a.x, t, a.x),
                       fmaf(b.y - a.y, t, a.y),
                       fmaf(b.z - a.z, t, a.z),
                       fmaf(b.w - a.w, t, a.w));
}

__global__ __launch_bounds__(128)
void crop_pool_kernel(const float* __restrict__ bottom,
                      const float* __restrict__ rois,
                      const float* __restrict__ im_info,
                      float* __restrict__ out,
                      int H, int W, int C, int N)
{
    const int blk = blockIdx.x;                 // n*49 + py*7 + px
    const int n  = blk / (POOLSZ * POOLSZ);
    const int p  = blk - n * (POOLSZ * POOLSZ);
    const int py = p / POOLSZ;
    const int px = p - py * POOLSZ;

    const float im_h = im_info[0];
    const float im_w = im_info[1];
    const float* r5 = rois + n * 5;
    const int   bid = (int)r5[0];
    const float x1 = r5[1] / im_w;
    const float y1 = r5[2] / im_h;
    const float x2 = r5[3] / im_w;
    const float y2 = r5[4] / im_h;

    // TF grid: coord = p1*(D-1) + i * ((p2-p1)*(D-1)/(CROP-1))
    const float sy = (y2 - y1) * (float)(H - 1) / (float)(CROPSZ - 1);
    const float sx = (x2 - x1) * (float)(W - 1) / (float)(CROPSZ - 1);
    const float oy = y1 * (float)(H - 1);
    const float ox = x1 * (float)(W - 1);

    int   y0i[2], y1i[2], x0i[2], x1i[2];
    float ly[2], lx[2];
    bool  vy[2], vx[2];
#pragma unroll
    for (int r = 0; r < 2; ++r) {
        const float ys = oy + (float)(2 * py + r) * sy;
        vy[r] = (ys >= 0.0f) && (ys <= (float)(H - 1));
        const float fy = floorf(ys);
        ly[r] = ys - fy;                               // unclipped, per reference
        y0i[r] = (int)fminf(fmaxf(fy, 0.0f), (float)(H - 1));
        y1i[r] = (int)fminf(fmaxf(ceilf(ys), 0.0f), (float)(H - 1));

        const float xv = ox + (float)(2 * px + r) * sx;
        vx[r] = (xv >= 0.0f) && (xv <= (float)(W - 1));
        const float fx = floorf(xv);
        lx[r] = xv - fx;
        x0i[r] = (int)fminf(fmaxf(fx, 0.0f), (float)(W - 1));
        x1i[r] = (int)fminf(fmaxf(ceilf(xv), 0.0f), (float)(W - 1));
    }

    const int C4  = C >> 2;                        // channels in float4 units
    const int tid = threadIdx.x;                   // one float4 of channels/thread
    const float4* __restrict__ bot4 = reinterpret_cast<const float4*>(bottom);

    float4 acc = make_float4(-INFINITY, -INFINITY, -INFINITY, -INFINITY);
#pragma unroll
    for (int r = 0; r < 2; ++r) {
        const int row0 = (bid * H + y0i[r]) * W;   // top corner row
        const int row1 = (bid * H + y1i[r]) * W;   // bottom corner row
#pragma unroll
        for (int s = 0; s < 2; ++s) {
            float4 v;
            if (vy[r] && vx[s]) {                  // block-uniform branch
                const float4 tl = bot4[(row0 + x0i[s]) * C4 + tid];
                const float4 tr = bot4[(row0 + x1i[s]) * C4 + tid];
                const float4 bl = bot4[(row1 + x0i[s]) * C4 + tid];
                const float4 br = bot4[(row1 + x1i[s]) * C4 + tid];
                const float4 top = lerp4(tl, tr, lx[s]);
                const float4 btm = lerp4(bl, br, lx[s]);
                v = lerp4(top, btm, ly[r]);
            } else {
                v = make_float4(0.0f, 0.0f, 0.0f, 0.0f);
            }
            acc = f4max(acc, v);
        }
    }

    float4* __restrict__ out4 = reinterpret_cast<float4*>(out);
    out4[(size_t)blk * C4 + tid] = acc;
}

extern "C" void kernel_launch(void* const* d_in, const int* in_sizes, int n_in,
                              void* d_out, int out_size, void* d_ws, size_t ws_size,
                              hipStream_t stream) {
    const float* bottom  = (const float*)d_in[0];
    const float* rois    = (const float*)d_in[1];
    const float* im_info = (const float*)d_in[2];
    float* out = (float*)d_out;

    const int H = 64, W = 64, C = 512;
    const int N = in_sizes[1] / 5;                 // 512 ROIs

    const int blocks = N * POOLSZ * POOLSZ;        // 25088
    crop_pool_kernel<<<blocks, 128, 0, stream>>>(bottom, rois, im_info, out,
                                                 H, W, C, N);
}

// Round 2
// 42.857 us; speedup vs baseline: 1.2109x; 1.2109x over previous
//
#include <hip/hip_runtime.h>
#include <math.h>

// CropPoolLayer: TF crop_and_resize (bilinear, extrapolation=0) to 14x14
// fused with 2x2 max pool -> [N,7,7,C], NHWC fp32.
// bottom [B=2,H=64,W=64,C=512] fp32, rois [N,5] (bid,x1,y1,x2,y2), im_info[2].
//
// R2: block = (ROI, pooled-row py). Scan the 14 sample columns with a
// 2-column register cache (x corners are monotone & block-uniform), cutting
// L2-side reads ~2.5x vs per-cell blocks. Bijective XCD swizzle keeps each
// ROI's 7 blocks (and neighboring ROIs) on one XCD's L2.

constexpr int POOLSZ = 7;
constexpr int CROPSZ = 14;

__device__ __forceinline__ float4 f4max(float4 a, float4 b) {
    return make_float4(fmaxf(a.x, b.x), fmaxf(a.y, b.y),
                       fmaxf(a.z, b.z), fmaxf(a.w, b.w));
}

// a + (b-a)*t  — matches reference lerp ordering
__device__ __forceinline__ float4 lerp4(float4 a, float4 b, float t) {
    return make_float4(fmaf(b.x - a.x, t, a.x),
                       fmaf(b.y - a.y, t, a.y),
                       fmaf(b.z - a.z, t, a.z),
                       fmaf(b.w - a.w, t, a.w));
}

__global__ __launch_bounds__(128)
void crop_pool_kernel(const float* __restrict__ bottom,
                      const float* __restrict__ rois,
                      const float* __restrict__ im_info,
                      float* __restrict__ out,
                      int nwg)
{
    constexpr int H = 64, W = 64, C4 = 128;   // C=512 -> 128 float4 lanes

    // Bijective XCD swizzle: hardware round-robins blockIdx across 8 XCDs;
    // remap so logical-contiguous blocks (same/neighbor ROI) share an XCD.
    const int bid = blockIdx.x;
    const int q = nwg >> 3, rr = nwg & 7;
    const int xcd = bid & 7, i = bid >> 3;
    const int blk = (xcd < rr ? xcd * (q + 1) : rr * (q + 1) + (xcd - rr) * q) + i;

    const int n  = blk / POOLSZ;              // ROI index
    const int py = blk - n * POOLSZ;          // pooled row

    const float im_h = im_info[0];
    const float im_w = im_info[1];
    const float* r5 = rois + n * 5;
    const int   bb  = (int)r5[0];
    const float rx1 = r5[1] / im_w;
    const float ry1 = r5[2] / im_h;
    const float rx2 = r5[3] / im_w;
    const float ry2 = r5[4] / im_h;

    // TF grid: coord = p1*(D-1) + i * ((p2-p1)*(D-1)/(CROP-1))
    const float sy = (ry2 - ry1) * (float)(H - 1) / (float)(CROPSZ - 1);
    const float sx = (rx2 - rx1) * (float)(W - 1) / (float)(CROPSZ - 1);
    const float oy = ry1 * (float)(H - 1);
    const float ox = rx1 * (float)(W - 1);

    const int tid = threadIdx.x;              // one float4 of channels
    const float4* __restrict__ bot4 = reinterpret_cast<const float4*>(bottom);

    float4 acc[POOLSZ];
#pragma unroll
    for (int p = 0; p < POOLSZ; ++p)
        acc[p] = make_float4(-INFINITY, -INFINITY, -INFINITY, -INFINITY);

    const float4 zero = make_float4(0.0f, 0.0f, 0.0f, 0.0f);

    for (int r = 0; r < 2; ++r) {
        const float ys  = oy + (float)(2 * py + r) * sy;
        const bool  vyr = (ys >= 0.0f) && (ys <= (float)(H - 1));
        if (!vyr) {                            // whole sample row is zeros
#pragma unroll
            for (int p = 0; p < POOLSZ; ++p) acc[p] = f4max(acc[p], zero);
            continue;
        }
        const float fy  = floorf(ys);
        const float lyr = ys - fy;             // unclipped, per reference
        const int y0 = (int)fminf(fmaxf(fy, 0.0f), (float)(H - 1));
        const int y1 = (int)fminf(fmaxf(ceilf(ys), 0.0f), (float)(H - 1));
        const float4* __restrict__ row0 = bot4 + (size_t)(bb * H + y0) * W * C4;
        const float4* __restrict__ row1 = bot4 + (size_t)(bb * H + y1) * W * C4;

        // two-column register cache; x corners are monotone & block-uniform
        int idxL = -1, idxR = -1;
        float4 L0, L1, R0, R1;
        L0 = L1 = R0 = R1 = zero;

        for (int j = 0; j < CROPSZ; ++j) {
            const float xv  = ox + (float)j * sx;
            const bool  vxj = (xv >= 0.0f) && (xv <= (float)(W - 1));
            float4 v;
            if (vxj) {
                const float fx  = floorf(xv);
                const float lxj = xv - fx;
                const int c0 = (int)fminf(fmaxf(fx, 0.0f), (float)(W - 1));
                const int c1 = (int)fminf(fmaxf(ceilf(xv), 0.0f), (float)(W - 1));
                if (c0 != idxL) {
                    if (c0 == idxR) { L0 = R0; L1 = R1; }
                    else {
                        L0 = row0[(size_t)c0 * C4 + tid];
                        L1 = row1[(size_t)c0 * C4 + tid];
                    }
                    idxL = c0;
                }
                if (c1 != idxR) {
                    if (c1 == idxL) { R0 = L0; R1 = L1; }
                    else {
                        R0 = row0[(size_t)c1 * C4 + tid];
                        R1 = row1[(size_t)c1 * C4 + tid];
                    }
                    idxR = c1;
                }
                // exact reference ordering: tl=L0, tr=R0, bl=L1, br=R1
                const float4 top = lerp4(L0, R0, lxj);
                const float4 btm = lerp4(L1, R1, lxj);
                v = lerp4(top, btm, lyr);
            } else {
                v = zero;
            }
            acc[j >> 1] = f4max(acc[j >> 1], v);
        }
    }

    float4* __restrict__ out4 = reinterpret_cast<float4*>(out);
    const size_t obase = ((size_t)n * POOLSZ + py) * POOLSZ;
#pragma unroll
    for (int p = 0; p < POOLSZ; ++p)
        out4[(obase + p) * C4 + tid] = acc[p];
}

extern "C" void kernel_launch(void* const* d_in, const int* in_sizes, int n_in,
                              void* d_out, int out_size, void* d_ws, size_t ws_size,
                              hipStream_t stream) {
    const float* bottom  = (const float*)d_in[0];
    const float* rois    = (const float*)d_in[1];
    const float* im_info = (const float*)d_in[2];
    float* out = (float*)d_out;

    const int N = in_sizes[1] / 5;            // 512 ROIs
    const int nwg = N * POOLSZ;               // 3584 blocks

    crop_pool_kernel<<<nwg, 128, 0, stream>>>(bottom, rois, im_info, out, nwg);
}